// Round 16
// baseline (195.518 us; speedup 1.0000x reference)
//
#include <hip/hip_runtime.h>

typedef _Float16 f16;
typedef f16  f16x8 __attribute__((ext_vector_type(8)));
typedef f16  f16x4 __attribute__((ext_vector_type(4)));
typedef __fp16 fp16x2 __attribute__((ext_vector_type(2)));
typedef float f32x4 __attribute__((ext_vector_type(4)));

__device__ __forceinline__ void gld_lds16(const f16* g, void* l) {
  __builtin_amdgcn_global_load_lds((const __attribute__((address_space(1))) void*)g,
                                   (__attribute__((address_space(3))) void*)l,
                                   16, 0, 0);
}

// pack 8 f32 -> f16x8 via v_cvt_pkrtz (RTZ)
__device__ __forceinline__ f16x8 pack8(float4 a, float4 b) {
  union { f16x8 v; fp16x2 h[4]; } u;
  u.h[0] = __builtin_amdgcn_cvt_pkrtz(a.x, a.y);
  u.h[1] = __builtin_amdgcn_cvt_pkrtz(a.z, a.w);
  u.h[2] = __builtin_amdgcn_cvt_pkrtz(b.x, b.y);
  u.h[3] = __builtin_amdgcn_cvt_pkrtz(b.z, b.w);
  return u.v;
}

enum { EPI_SCORES = 0, EPI_RELU = 2, EPI_OUT = 3, EPI_BIASR = 4 };

// C[M,N] = A[M,K] @ B[N,K]^T, 128x128 tile, BK=32, 4 waves (2x2), 16x16x32 f16 MFMA.
// 4-stage LDS pipeline, counted vmcnt drain 8->4->0, raw s_barrier, swizzled LDS.
// NOTE (R6): keep 128x128 with >=2 blocks/CU; fatter tiles at 1 block/CU regressed.
template<int EPI, bool XMAP>
__global__ __launch_bounds__(256)
void gemm_bt(const f16* __restrict__ A, const f16* __restrict__ B, void* __restrict__ C,
             int lda, int ldb, int ldc, int K,
             long long sA, long long sB, long long sC,
             const float* __restrict__ bias, float scale,
             const float* __restrict__ wfb, const float* __restrict__ dvv,
             int nx, int nbz)
{
  __shared__ __align__(16) f16 As[4][128][32];
  __shared__ __align__(16) f16 Bs[4][128][32];
  const int tid  = threadIdx.x;
  const int lane = tid & 63;
  const int w    = tid >> 6;
  const int wm   = w >> 1, wn = w & 1;

  const int lin = blockIdx.x;
  int bz, bj;
  if constexpr (XMAP) {
    const int xcd = lin & 7, rest = lin >> 3;
    const int grp = rest / nbz;
    bj = rest - grp * nbz;
    bz = xcd + (grp << 3);
  } else {
    bz = lin / nbz; bj = lin - bz * nbz;
  }
  const int m0 = (bj / nx) * 128, n0 = (bj % nx) * 128;
  const f16* Ab = A + (size_t)bz * sA + (size_t)m0 * lda;
  const f16* Bb = B + (size_t)bz * sB + (size_t)n0 * ldb;

  f32x4 acc[4][4] = {};
  const int nsteps = K >> 5;

#define STAGE(bufb, ks)                                                              \
  {                                                                                  \
    const int k0_ = (ks) << 5;                                                       \
    _Pragma("unroll")                                                                \
    for (int i = 0; i < 2; ++i) {                                                    \
      const int ci = i * 256 + tid;                                                  \
      const int r  = ci >> 2;                                                        \
      const int sg = (ci & 3) ^ ((r >> 1) & 3);                                      \
      gld_lds16(Ab + (size_t)r * lda + k0_ + sg * 8,                                 \
                (char*)As + (bufb) + (size_t)(i * 256 + w * 64) * 16);               \
      gld_lds16(Bb + (size_t)r * ldb + k0_ + sg * 8,                                 \
                (char*)Bs + (bufb) + (size_t)(i * 256 + w * 64) * 16);               \
    }                                                                                \
  }

  STAGE(0, 0)
  if (1 < nsteps) STAGE(8192, 1)
  if (2 < nsteps) STAGE(16384, 2)

  const int elemoff = (((lane >> 4) ^ ((lane >> 1) & 3)) << 3);

  int cur = 0;
  for (int t = 0; t < nsteps; ++t) {
    if (t + 2 < nsteps)      asm volatile("s_waitcnt vmcnt(8)" ::: "memory");
    else if (t + 1 < nsteps) asm volatile("s_waitcnt vmcnt(4)" ::: "memory");
    else                     asm volatile("s_waitcnt vmcnt(0)" ::: "memory");
    __builtin_amdgcn_s_barrier();
    __builtin_amdgcn_sched_barrier(0);
    if (t + 3 < nsteps) STAGE(((cur + 3) & 3) * 8192, t + 3)
    f16x8 af[4], bfr[4];
#pragma unroll
    for (int m = 0; m < 4; ++m)
      af[m] = *(const f16x8*)&As[cur][wm * 64 + m * 16 + (lane & 15)][elemoff];
#pragma unroll
    for (int n = 0; n < 4; ++n)
      bfr[n] = *(const f16x8*)&Bs[cur][wn * 64 + n * 16 + (lane & 15)][elemoff];
    __builtin_amdgcn_s_setprio(1);
#pragma unroll
    for (int m = 0; m < 4; ++m)
#pragma unroll
      for (int n = 0; n < 4; ++n)
        acc[m][n] = __builtin_amdgcn_mfma_f32_16x16x32_f16(af[m], bfr[n], acc[m][n], 0, 0, 0);
    __builtin_amdgcn_s_setprio(0);
    cur = (cur + 1) & 3;
  }
#undef STAGE

  const int col_l = lane & 15;
  const int row_l = (lane >> 4) << 2;

  {
    f16* Ch = (f16*)C + (size_t)bz * sC + (size_t)m0 * ldc + n0;
#pragma unroll
    for (int m = 0; m < 4; ++m)
#pragma unroll
      for (int n = 0; n < 4; ++n)
#pragma unroll
        for (int r = 0; r < 4; ++r) {
          const int rr = wm * 64 + m * 16 + row_l + r;
          const int cc = wn * 64 + n * 16 + col_l;
          float val = acc[m][n][r];
          if constexpr (EPI == EPI_RELU) { val += bias[n0 + cc]; val = fmaxf(val, 0.0f); }
          if constexpr (EPI == EPI_BIASR) val += bias[m0 + rr];
          if constexpr (EPI == EPI_OUT)
            val += wfb[bz * 1024 + m0 + rr] * dvv[bz * 512 + n0 + cc];
          Ch[(size_t)rr * ldc + cc] = (f16)val;
        }
  }
  (void)scale;
}

// 256x256 scores GEMM reading q,k in f32, REG-STAGED to f16 LDS (proven R14):
// f32 -> regs -> cvt_pkrtz -> ds_write_b128; 3 buffers, one __syncthreads/step.
__global__ __launch_bounds__(512, 2)
void gemm256_scores(const float* __restrict__ A, const float* __restrict__ B, f16* __restrict__ C,
                    float scale, float* __restrict__ mmarr)
{
  __shared__ __align__(16) f16 As[3][256][32];
  __shared__ __align__(16) f16 Bs[3][256][32];
  __shared__ float redm[8], redn[8];
  const int tid  = threadIdx.x;
  const int lane = tid & 63;
  const int w    = tid >> 6;           // 0..7
  const int wm   = w >> 2, wn = w & 3; // 2 x 4
  const int lin  = blockIdx.x;
  const int xcd = lin & 7, rest = lin >> 3;
  const int bj  = rest & 15;
  const int bz  = xcd + ((rest >> 4) << 3);
  const int m0 = (bj >> 2) * 256, n0 = (bj & 3) * 256;
  const float* Ab = A + (size_t)bz * 524288 + (size_t)m0 * 512;
  const float* Bb = B + (size_t)bz * 524288 + (size_t)n0 * 512;

  const int r0  = tid >> 2;
  const int sg0 = (tid & 3) ^ ((r0 >> 1) & 3);
  const size_t offG = (size_t)r0 * 512 + sg0 * 8;      // f32 offset
  f16* const dstA0 = (f16*)As + (size_t)tid * 8;       // + buf*8192
  f16* const dstB0 = (f16*)Bs + (size_t)tid * 8;

  f32x4 acc[8][4] = {};

#pragma unroll
  for (int s = 0; s < 2; ++s) {
    const int k0 = s << 5;
    float4 a0 = *(const float4*)(Ab + offG + k0);
    float4 a1 = *(const float4*)(Ab + offG + k0 + 4);
    float4 a2 = *(const float4*)(Ab + offG + k0 + 65536);
    float4 a3 = *(const float4*)(Ab + offG + k0 + 65540);
    float4 b0 = *(const float4*)(Bb + offG + k0);
    float4 b1 = *(const float4*)(Bb + offG + k0 + 4);
    float4 b2 = *(const float4*)(Bb + offG + k0 + 65536);
    float4 b3 = *(const float4*)(Bb + offG + k0 + 65540);
    *(f16x8*)(dstA0 + s * 8192)        = pack8(a0, a1);
    *(f16x8*)(dstA0 + s * 8192 + 4096) = pack8(a2, a3);
    *(f16x8*)(dstB0 + s * 8192)        = pack8(b0, b1);
    *(f16x8*)(dstB0 + s * 8192 + 4096) = pack8(b2, b3);
  }
  __syncthreads();

  const int fr = lane & 15;
  const int elemoff = (((lane >> 4) ^ ((lane >> 1) & 3)) << 3);  // f16 elements

  int cur = 0;
  for (int t = 0; t < 16; ++t) {
    float4 a0, a1, a2, a3, b0, b1, b2, b3;
    if (t + 2 < 16) {
      const int k0 = (t + 2) << 5;
      a0 = *(const float4*)(Ab + offG + k0);
      a1 = *(const float4*)(Ab + offG + k0 + 4);
      a2 = *(const float4*)(Ab + offG + k0 + 65536);
      a3 = *(const float4*)(Ab + offG + k0 + 65540);
      b0 = *(const float4*)(Bb + offG + k0);
      b1 = *(const float4*)(Bb + offG + k0 + 4);
      b2 = *(const float4*)(Bb + offG + k0 + 65536);
      b3 = *(const float4*)(Bb + offG + k0 + 65540);
    }
    f16x8 af[8], bfr[4];
#pragma unroll
    for (int m = 0; m < 8; ++m)
      af[m] = *(const f16x8*)&As[cur][wm * 128 + m * 16 + fr][elemoff];
#pragma unroll
    for (int n = 0; n < 4; ++n)
      bfr[n] = *(const f16x8*)&Bs[cur][wn * 64 + n * 16 + fr][elemoff];
    __builtin_amdgcn_s_setprio(1);
#pragma unroll
    for (int m = 0; m < 8; ++m)
#pragma unroll
      for (int n = 0; n < 4; ++n)
        acc[m][n] = __builtin_amdgcn_mfma_f32_16x16x32_f16(af[m], bfr[n], acc[m][n], 0, 0, 0);
    __builtin_amdgcn_s_setprio(0);
    if (t + 2 < 16) {
      int wb = cur + 2; if (wb >= 3) wb -= 3;
      *(f16x8*)(dstA0 + wb * 8192)        = pack8(a0, a1);
      *(f16x8*)(dstA0 + wb * 8192 + 4096) = pack8(a2, a3);
      *(f16x8*)(dstB0 + wb * 8192)        = pack8(b0, b1);
      *(f16x8*)(dstB0 + wb * 8192 + 4096) = pack8(b2, b3);
    }
    __syncthreads();
    cur = (cur + 1 == 3) ? 0 : cur + 1;
  }

  const int col_l = lane & 15;
  const int row_l = (lane >> 4) << 2;
  f16* Ch = C + (size_t)bz * 1048576 + (size_t)m0 * 1024 + n0;
  float lmax = -3.402823466e38f, lmin = 3.402823466e38f;
#pragma unroll
  for (int m = 0; m < 8; ++m)
#pragma unroll
    for (int n = 0; n < 4; ++n)
#pragma unroll
      for (int r = 0; r < 4; ++r) {
        float val = acc[m][n][r] * scale;
        lmax = fmaxf(lmax, val); lmin = fminf(lmin, val);
        Ch[(size_t)(wm * 128 + m * 16 + row_l + r) * 1024 + (wn * 64 + n * 16 + col_l)] = (f16)val;
      }
#pragma unroll
  for (int off = 32; off >= 1; off >>= 1) {
    lmax = fmaxf(lmax, __shfl_xor(lmax, off));
    lmin = fminf(lmin, __shfl_xor(lmin, off));
  }
  if (lane == 0) { redm[w] = lmax; redn[w] = lmin; }
  __syncthreads();
  if (tid == 0) {
    float gm = redm[0], gn = redn[0];
#pragma unroll
    for (int i = 1; i < 8; ++i) { gm = fmaxf(gm, redm[i]); gn = fminf(gn, redn[i]); }
    mmarr[lin] = gm; mmarr[256 + lin] = gn;
  }
}

// Merged softmax + vpt dispatch. Blocks [0,16384): row softmax (each block re-reduces
// mmarr -> fb locally: identical sequence per block -> bitwise-identical fb, no extra
// dispatch). Blocks [16384,16896): vpt = Wv16 @ v^T + bv (reg-staged f32 B, validated
// R15). One 48KB smem blob unioned across branches -> 3 blocks/CU both ways.
__global__ __launch_bounds__(256)
void smvp(const f16* __restrict__ scores, const void* __restrict__ maskp,
          const float* __restrict__ fallback, const float* __restrict__ mmarr,
          const unsigned* __restrict__ mm,
          f16* __restrict__ Wt, float* __restrict__ wfb,
          const f16* __restrict__ Wv16, const float* __restrict__ v,
          f16* __restrict__ vpt, const float* __restrict__ bv)
{
  __shared__ __align__(16) char smem[49152];
  const int blk  = blockIdx.x;
  const int tid  = threadIdx.x;
  const int lane = tid & 63;
  const int w    = tid >> 6;

  if (blk < 16384) {
    float* red = (float*)smem;   // 8 floats scratch
    // --- per-block fb reduction over mmarr (256 max + 256 min) ---
    float mx0 = mmarr[tid];
    float mn0 = mmarr[256 + tid];
#pragma unroll
    for (int off = 32; off >= 1; off >>= 1) {
      mx0 = fmaxf(mx0, __shfl_xor(mx0, off));
      mn0 = fminf(mn0, __shfl_xor(mn0, off));
    }
    if (lane == 0) { red[w] = mx0; red[4 + w] = mn0; }
    __syncthreads();
    const float gmax = fmaxf(fmaxf(red[0], red[1]), fmaxf(red[2], red[3]));
    const float gmin = fminf(fminf(red[4], red[5]), fminf(red[6], red[7]));
    const float fb = 0.99f * fallback[0] + 0.005f * (gmax + gmin);
    const unsigned mode = (mm[0] > 5000u) ? 1u : 0u;
    __syncthreads();
    // --- softmax over row ---
    const int row = blk;
    const int b   = row >> 10;
    const f16* s = scores + (size_t)row * 1024;
    const int k0 = tid * 4;
    f16x4 sv = *(const f16x4*)(s + k0);
    float x[4];
    if (mode) {
      const unsigned char* m8 = (const unsigned char*)maskp + b * 1024 + k0;
      x[0] = m8[0] ? -1e9f : (float)sv[0];  x[1] = m8[1] ? -1e9f : (float)sv[1];
      x[2] = m8[2] ? -1e9f : (float)sv[2];  x[3] = m8[3] ? -1e9f : (float)sv[3];
    } else {
      const int* mi = (const int*)maskp + b * 1024 + k0;
      x[0] = mi[0] ? -1e9f : (float)sv[0];  x[1] = mi[1] ? -1e9f : (float)sv[1];
      x[2] = mi[2] ? -1e9f : (float)sv[2];  x[3] = mi[3] ? -1e9f : (float)sv[3];
    }
    float mx = fmaxf(fmaxf(x[0], x[1]), fmaxf(x[2], x[3]));
#pragma unroll
    for (int off = 32; off >= 1; off >>= 1) mx = fmaxf(mx, __shfl_xor(mx, off));
    if (lane == 0) red[w] = mx;
    __syncthreads();
    mx = fmaxf(fmaxf(fmaxf(red[0], red[1]), fmaxf(red[2], red[3])), fb);
    float e0 = expf(x[0] - mx), e1 = expf(x[1] - mx), e2 = expf(x[2] - mx), e3 = expf(x[3] - mx);
    float sum = (e0 + e1) + (e2 + e3);
#pragma unroll
    for (int off = 32; off >= 1; off >>= 1) sum += __shfl_xor(sum, off);
    if (lane == 0) red[4 + w] = sum;
    __syncthreads();
    float efb = expf(fb - mx);
    float Z = ((red[4] + red[5]) + (red[6] + red[7])) + efb;
    float inv = 1.0f / Z;
    f16x4 o = { (f16)(e0 * inv), (f16)(e1 * inv), (f16)(e2 * inv), (f16)(e3 * inv) };
    *(f16x4*)&Wt[(size_t)row * 1024 + k0] = o;
    if (tid == 0) wfb[row] = efb * inv;
  } else {
    // --- vpt: 128x128 tile, 4 waves, 3-buffer reg-staged (validated R15) ---
    f16* const AsB = (f16*)smem;           // 3*128*32 = 12288 f16 (24KB)
    f16* const BsB = AsB + 12288;
    const int wm = w >> 1, wn = w & 1;
    const int lin  = blk - 16384;
    const int xcd = lin & 7, rest = lin >> 3;
    const int grp = rest >> 5, bj = rest & 31;
    const int bz  = xcd + (grp << 3);
    const int m0 = (bj >> 3) * 128, n0 = (bj & 7) * 128;
    const f16*   Ab = Wv16 + (size_t)m0 * 512;
    const float* Bb = v + (size_t)bz * 524288 + (size_t)n0 * 512;

    const int r0  = tid >> 2;
    const int sg0 = (tid & 3) ^ ((r0 >> 1) & 3);
    const size_t offA = (size_t)r0 * 512 + sg0 * 8;   // f16 elems
    const size_t offB = (size_t)r0 * 512 + sg0 * 8;   // f32 elems
    f16* const dstA0 = AsB + (size_t)tid * 8;         // + buf*4096
    f16* const dstB0 = BsB + (size_t)tid * 8;

    f32x4 acc[4][4] = {};

#pragma unroll
    for (int s = 0; s < 2; ++s) {
      const int k0 = s << 5;
      f16x8  a0 = *(const f16x8*)(Ab + offA + k0);
      f16x8  a1 = *(const f16x8*)(Ab + offA + k0 + 32768);
      float4 b0 = *(const float4*)(Bb + offB + k0);
      float4 b1 = *(const float4*)(Bb + offB + k0 + 4);
      float4 b2 = *(const float4*)(Bb + offB + k0 + 32768);
      float4 b3 = *(const float4*)(Bb + offB + k0 + 32772);
      *(f16x8*)(dstA0 + s * 4096)        = a0;
      *(f16x8*)(dstA0 + s * 4096 + 2048) = a1;
      *(f16x8*)(dstB0 + s * 4096)        = pack8(b0, b1);
      *(f16x8*)(dstB0 + s * 4096 + 2048) = pack8(b2, b3);
    }
    __syncthreads();

    const int fr = lane & 15;
    const int elemoff = (((lane >> 4) ^ ((lane >> 1) & 3)) << 3);

    int cur = 0;
    for (int t = 0; t < 16; ++t) {
      f16x8  a0, a1; float4 b0, b1, b2, b3;
      if (t + 2 < 16) {
        const int k0 = (t + 2) << 5;
        a0 = *(const f16x8*)(Ab + offA + k0);
        a1 = *(const f16x8*)(Ab + offA + k0 + 32768);
        b0 = *(const float4*)(Bb + offB + k0);
        b1 = *(const float4*)(Bb + offB + k0 + 4);
        b2 = *(const float4*)(Bb + offB + k0 + 32768);
        b3 = *(const float4*)(Bb + offB + k0 + 32772);
      }
      f16x8 af[4], bfr[4];
#pragma unroll
      for (int m = 0; m < 4; ++m)
        af[m] = *(const f16x8*)(AsB + cur * 4096 + (wm * 64 + m * 16 + fr) * 32 + elemoff);
#pragma unroll
      for (int n = 0; n < 4; ++n)
        bfr[n] = *(const f16x8*)(BsB + cur * 4096 + (wn * 64 + n * 16 + fr) * 32 + elemoff);
      __builtin_amdgcn_s_setprio(1);
#pragma unroll
      for (int m = 0; m < 4; ++m)
#pragma unroll
        for (int n = 0; n < 4; ++n)
          acc[m][n] = __builtin_amdgcn_mfma_f32_16x16x32_f16(af[m], bfr[n], acc[m][n], 0, 0, 0);
      __builtin_amdgcn_s_setprio(0);
      if (t + 2 < 16) {
        int wb = cur + 2; if (wb >= 3) wb -= 3;
        *(f16x8*)(dstA0 + wb * 4096)        = a0;
        *(f16x8*)(dstA0 + wb * 4096 + 2048) = a1;
        *(f16x8*)(dstB0 + wb * 4096)        = pack8(b0, b1);
        *(f16x8*)(dstB0 + wb * 4096 + 2048) = pack8(b2, b3);
      }
      __syncthreads();
      cur = (cur + 1 == 3) ? 0 : cur + 1;
    }

    const int col_l = lane & 15;
    const int row_l = (lane >> 4) << 2;
    f16* Ch = vpt + (size_t)bz * 524288 + (size_t)m0 * 1024 + n0;
#pragma unroll
    for (int m = 0; m < 4; ++m)
#pragma unroll
      for (int n = 0; n < 4; ++n)
#pragma unroll
        for (int r = 0; r < 4; ++r) {
          const int rr = wm * 64 + m * 16 + row_l + r;
          const int cc = wn * 64 + n * 16 + col_l;
          Ch[(size_t)rr * 1024 + cc] = (f16)(acc[m][n][r] + bv[m0 + rr]);
        }
  }
}

// merged front work: [0,640) weight converts; [640,2688) dv FC; [2688] mask sniff
__global__ __launch_bounds__(256)
void front_k(const float* __restrict__ wv, const float* __restrict__ w1,
             const float* __restrict__ w2,
             f16* __restrict__ owv, f16* __restrict__ ow1, f16* __restrict__ ow2,
             const float* __restrict__ uq, const float* __restrict__ Wf,
             const float* __restrict__ bfv, float* __restrict__ dv,
             const unsigned char* __restrict__ mask, unsigned* __restrict__ mm)
{
  const int blk = blockIdx.x;
  if (blk < 640) {
    int i = blk * 256 + threadIdx.x;   // 0..163839
    const float* src; f16* dst; int j;
    if (i < 65536)       { src = wv; dst = owv; j = i; }
    else if (i < 131072) { src = w1; dst = ow1; j = i - 65536; }
    else                 { src = w2; dst = ow2; j = i - 131072; }
    float4 x = *(const float4*)(src + (size_t)j * 4);
    f16x4 o = { (f16)x.x, (f16)x.y, (f16)x.z, (f16)x.w };
    *(f16x4*)(dst + (size_t)j * 4) = o;
  } else if (blk < 2688) {
    const int gw   = ((blk - 640) * 256 + threadIdx.x) >> 6;  // 0..8191
    const int lane = threadIdx.x & 63;
    const int b = gw >> 9, j = gw & 511;
    const float* x  = uq + (size_t)b * 512;
    const float* wr = Wf + (size_t)j * 512;
    const int o = lane * 8;
    float4 x0 = *(const float4*)(x + o),  x1 = *(const float4*)(x + o + 4);
    float4 w0 = *(const float4*)(wr + o), w1v = *(const float4*)(wr + o + 4);
    float s = x0.x*w0.x + x0.y*w0.y + x0.z*w0.z + x0.w*w0.w
            + x1.x*w1v.x + x1.y*w1v.y + x1.z*w1v.z + x1.w*w1v.w;
#pragma unroll
    for (int off = 32; off >= 1; off >>= 1) s += __shfl_xor(s, off);
    if (lane == 0) dv[gw] = s + bfv[j];
  } else {
    __shared__ int redc[256];
    int c = 0;
    for (int i = threadIdx.x; i < 16384; i += 256) c += (mask[i] != 0) ? 1 : 0;
    redc[threadIdx.x] = c;
    __syncthreads();
    for (int s = 128; s > 0; s >>= 1) {
      if (threadIdx.x < s) redc[threadIdx.x] += redc[threadIdx.x + s];
      __syncthreads();
    }
    if (threadIdx.x == 0) mm[0] = (unsigned)redc[0];
  }
}

// wave-per-output FC: Y[b,j] = act(X[b,:] . W[j,:] + bias[j])
template<int IN, int ACT>
__global__ __launch_bounds__(256)
void fc_wave(const float* __restrict__ X, const float* __restrict__ W,
             const float* __restrict__ bias, float* __restrict__ Y, int OutN)
{
  const int gw   = (blockIdx.x * 256 + threadIdx.x) >> 6;
  const int lane = threadIdx.x & 63;
  const int b = gw / OutN, j = gw - b * OutN;
  const float* x  = X + (size_t)b * IN;
  const float* wr = W + (size_t)j * IN;
  float s = 0.f;
  if constexpr (IN == 512) {
    const int o = lane * 8;
    float4 x0 = *(const float4*)(x + o),  x1 = *(const float4*)(x + o + 4);
    float4 w0 = *(const float4*)(wr + o), w1 = *(const float4*)(wr + o + 4);
    s = x0.x*w0.x + x0.y*w0.y + x0.z*w0.z + x0.w*w0.w
      + x1.x*w1.x + x1.y*w1.y + x1.z*w1.z + x1.w*w1.w;
  } else {
    const int o = lane * 4;
    float4 x0 = *(const float4*)(x + o);
    float4 w0 = *(const float4*)(wr + o);
    s = x0.x*w0.x + x0.y*w0.y + x0.z*w0.z + x0.w*w0.w;
  }
#pragma unroll
  for (int off = 32; off >= 1; off >>= 1) s += __shfl_xor(s, off);
  if (lane == 0) {
    float val = s + bias[ACT == 2 ? 0 : j];
    if constexpr (ACT == 1) val = fmaxf(val, 0.f);
    if constexpr (ACT == 2) val = tanhf(val);
    Y[gw] = val;
  }
}

__global__ __launch_bounds__(256)
void y_kernel(const f16* __restrict__ h2, const float* __restrict__ W3,
              const float* __restrict__ b3, float* __restrict__ outp)
{
  int row = blockIdx.x * 16 + (threadIdx.x >> 4);
  int l   = threadIdx.x & 15;
  const f16* h = h2 + (size_t)row * 256 + l * 16;
  float s = 0.f;
#pragma unroll
  for (int j = 0; j < 16; ++j) s += (float)h[j] * W3[l * 16 + j];
#pragma unroll
  for (int off = 1; off < 16; off <<= 1) s += __shfl_xor(s, off);
  if (l == 0) outp[row] = tanhf(s + b3[0]);
}

extern "C" void kernel_launch(void* const* d_in, const int* in_sizes, int n_in,
                              void* d_out, int out_size, void* d_ws, size_t ws_size,
                              hipStream_t stream) {
  const float* uq       = (const float*)d_in[0];
  const float* q        = (const float*)d_in[1];
  const float* kk       = (const float*)d_in[2];
  const float* v        = (const float*)d_in[3];
  const void*  mask     = d_in[4];
  const float* fallback = (const float*)d_in[5];
  const float* Wv = (const float*)d_in[6];
  const float* bv = (const float*)d_in[7];
  const float* Wf = (const float*)d_in[8];
  const float* bf = (const float*)d_in[9];
  const float* W1 = (const float*)d_in[10];
  const float* b1 = (const float*)d_in[11];
  const float* W2 = (const float*)d_in[12];
  const float* b2 = (const float*)d_in[13];
  const float* W3 = (const float*)d_in[14];
  const float* b3 = (const float*)d_in[15];
  float* outp = (float*)d_out;

  char* ws = (char*)d_ws;
  const size_t MB = 1ull << 20;
  f16*  scores = (f16*)ws;
  f16*  h1b  = (f16*)ws;
  f16*  h2b  = (f16*)(ws + 16 * MB);
  f16*  vpt  = (f16*)(ws + 32 * MB);
  f16*  outb = (f16*)(ws + 48 * MB);
  f16*  wts  = (f16*)(ws + 64 * MB);
  char* cst  = ws + 112 * MB;
  f16*  Wv16 = (f16*)(cst);
  f16*  W116 = (f16*)(cst + 512 * 1024);
  f16*  W216 = (f16*)(cst + 1024 * 1024);
  float* dv   = (float*)(cst + 1280 * 1024);
  float* wfb  = (float*)(cst + 1312 * 1024);
  float* h1d  = (float*)(cst + 1376 * 1024);
  float* h2d  = (float*)(cst + 1408 * 1024);
  unsigned* mm = (unsigned*)(cst + 1424 * 1024);
  float* mmarr = (float*)(cst + 1432 * 1024);   // 2 * 256 floats

  // weight converts + dv FC + mask sniff
  front_k<<<2689, 256, 0, stream>>>(Wv, W1, W2, Wv16, W116, W216,
                                    uq, Wf, bf, dv,
                                    (const unsigned char*)mask, mm);

  // scores = q @ k^T / sqrt(512) -> f16, q/k read as f32, reg-staged to f16 LDS
  gemm256_scores<<<256, 512, 0, stream>>>(q, kk, scores, 0.04419417382415922f, mmarr);

  // merged: row softmax (fb reduced per block) + vpt GEMM
  smvp<<<16896, 256, 0, stream>>>(scores, mask, fallback, mmarr, mm,
                                  wts, wfb, Wv16, v, vpt, bv);

  // out = weights @ vp + wfb*dv
  gemm_bt<EPI_OUT, true><<<512, 256, 0, stream>>>(
      wts, vpt, outb, 1024, 1024, 512, 1024,
      1048576LL, 524288LL, 524288LL,
      nullptr, 1.f, wfb, dv, 4, 32);

  // h1 = relu(out @ W1^T + b1)
  gemm_bt<EPI_RELU, false><<<512, 256, 0, stream>>>(
      outb, W116, h1b, 512, 512, 512, 512, 0LL, 0LL, 0LL,
      b1, 1.f, nullptr, nullptr, 4, 512);

  // h2 = relu(h1 @ W2^T + b2)
  gemm_bt<EPI_RELU, false><<<256, 256, 0, stream>>>(
      h1b, W216, h2b, 512, 512, 256, 512, 0LL, 0LL, 0LL,
      b2, 1.f, nullptr, nullptr, 2, 256);

  y_kernel<<<1024, 256, 0, stream>>>(h2b, W3, b3, outp);

  // default-values scorer branch (f32, wave-per-output)
  fc_wave<512, 1><<<2048, 256, 0, stream>>>(dv, W1, b1, h1d, 512);
  fc_wave<512, 1><<<1024, 256, 0, stream>>>(h1d, W2, b2, h2d, 256);
  fc_wave<256, 2><<<4, 256, 0, stream>>>(h2d, W3, b3, outp + 16384, 1);

  (void)in_sizes; (void)n_in; (void)out_size; (void)ws_size;
}

// Round 17
// 161.342 us; speedup vs baseline: 1.2118x; 1.2118x over previous
//
#include <hip/hip_runtime.h>

typedef _Float16 f16;
typedef f16  f16x8 __attribute__((ext_vector_type(8)));
typedef f16  f16x4 __attribute__((ext_vector_type(4)));
typedef __fp16 fp16x2 __attribute__((ext_vector_type(2)));
typedef float f32x4 __attribute__((ext_vector_type(4)));

__device__ __forceinline__ void gld_lds16(const f16* g, void* l) {
  __builtin_amdgcn_global_load_lds((const __attribute__((address_space(1))) void*)g,
                                   (__attribute__((address_space(3))) void*)l,
                                   16, 0, 0);
}

// pack 8 f32 -> f16x8 via v_cvt_pkrtz (RTZ)
__device__ __forceinline__ f16x8 pack8(float4 a, float4 b) {
  union { f16x8 v; fp16x2 h[4]; } u;
  u.h[0] = __builtin_amdgcn_cvt_pkrtz(a.x, a.y);
  u.h[1] = __builtin_amdgcn_cvt_pkrtz(a.z, a.w);
  u.h[2] = __builtin_amdgcn_cvt_pkrtz(b.x, b.y);
  u.h[3] = __builtin_amdgcn_cvt_pkrtz(b.z, b.w);
  return u.v;
}

enum { EPI_SCORES = 0, EPI_RELU = 2, EPI_OUT = 3, EPI_BIASR = 4 };

// C[M,N] = A[M,K] @ B[N,K]^T, 128x128 tile, BK=32, 4 waves (2x2), 16x16x32 f16 MFMA.
// 4-stage LDS pipeline, counted vmcnt drain 8->4->0, raw s_barrier, swizzled LDS.
// NOTE (R6): keep 128x128 with >=2 blocks/CU; fatter tiles at 1 block/CU regressed.
// NOTE (R16): never merge this with a memory-bound kernel — branch union inherits
// the max LDS/VGPR footprint and collapses the memory kernel's occupancy.
template<int EPI, bool XMAP>
__global__ __launch_bounds__(256)
void gemm_bt(const f16* __restrict__ A, const f16* __restrict__ B, void* __restrict__ C,
             int lda, int ldb, int ldc, int K,
             long long sA, long long sB, long long sC,
             const float* __restrict__ bias, float scale,
             const float* __restrict__ wfb, const float* __restrict__ dvv,
             int nx, int nbz)
{
  __shared__ __align__(16) f16 As[4][128][32];
  __shared__ __align__(16) f16 Bs[4][128][32];
  const int tid  = threadIdx.x;
  const int lane = tid & 63;
  const int w    = tid >> 6;
  const int wm   = w >> 1, wn = w & 1;

  const int lin = blockIdx.x;
  int bz, bj;
  if constexpr (XMAP) {
    const int xcd = lin & 7, rest = lin >> 3;
    const int grp = rest / nbz;
    bj = rest - grp * nbz;
    bz = xcd + (grp << 3);
  } else {
    bz = lin / nbz; bj = lin - bz * nbz;
  }
  const int m0 = (bj / nx) * 128, n0 = (bj % nx) * 128;
  const f16* Ab = A + (size_t)bz * sA + (size_t)m0 * lda;
  const f16* Bb = B + (size_t)bz * sB + (size_t)n0 * ldb;

  f32x4 acc[4][4] = {};
  const int nsteps = K >> 5;

#define STAGE(bufb, ks)                                                              \
  {                                                                                  \
    const int k0_ = (ks) << 5;                                                       \
    _Pragma("unroll")                                                                \
    for (int i = 0; i < 2; ++i) {                                                    \
      const int ci = i * 256 + tid;                                                  \
      const int r  = ci >> 2;                                                        \
      const int sg = (ci & 3) ^ ((r >> 1) & 3);                                      \
      gld_lds16(Ab + (size_t)r * lda + k0_ + sg * 8,                                 \
                (char*)As + (bufb) + (size_t)(i * 256 + w * 64) * 16);               \
      gld_lds16(Bb + (size_t)r * ldb + k0_ + sg * 8,                                 \
                (char*)Bs + (bufb) + (size_t)(i * 256 + w * 64) * 16);               \
    }                                                                                \
  }

  STAGE(0, 0)
  if (1 < nsteps) STAGE(8192, 1)
  if (2 < nsteps) STAGE(16384, 2)

  const int elemoff = (((lane >> 4) ^ ((lane >> 1) & 3)) << 3);

  int cur = 0;
  for (int t = 0; t < nsteps; ++t) {
    if (t + 2 < nsteps)      asm volatile("s_waitcnt vmcnt(8)" ::: "memory");
    else if (t + 1 < nsteps) asm volatile("s_waitcnt vmcnt(4)" ::: "memory");
    else                     asm volatile("s_waitcnt vmcnt(0)" ::: "memory");
    __builtin_amdgcn_s_barrier();
    __builtin_amdgcn_sched_barrier(0);
    if (t + 3 < nsteps) STAGE(((cur + 3) & 3) * 8192, t + 3)
    f16x8 af[4], bfr[4];
#pragma unroll
    for (int m = 0; m < 4; ++m)
      af[m] = *(const f16x8*)&As[cur][wm * 64 + m * 16 + (lane & 15)][elemoff];
#pragma unroll
    for (int n = 0; n < 4; ++n)
      bfr[n] = *(const f16x8*)&Bs[cur][wn * 64 + n * 16 + (lane & 15)][elemoff];
    __builtin_amdgcn_s_setprio(1);
#pragma unroll
    for (int m = 0; m < 4; ++m)
#pragma unroll
      for (int n = 0; n < 4; ++n)
        acc[m][n] = __builtin_amdgcn_mfma_f32_16x16x32_f16(af[m], bfr[n], acc[m][n], 0, 0, 0);
    __builtin_amdgcn_s_setprio(0);
    cur = (cur + 1) & 3;
  }
#undef STAGE

  const int col_l = lane & 15;
  const int row_l = (lane >> 4) << 2;

  {
    f16* Ch = (f16*)C + (size_t)bz * sC + (size_t)m0 * ldc + n0;
#pragma unroll
    for (int m = 0; m < 4; ++m)
#pragma unroll
      for (int n = 0; n < 4; ++n)
#pragma unroll
        for (int r = 0; r < 4; ++r) {
          const int rr = wm * 64 + m * 16 + row_l + r;
          const int cc = wn * 64 + n * 16 + col_l;
          float val = acc[m][n][r];
          if constexpr (EPI == EPI_RELU) { val += bias[n0 + cc]; val = fmaxf(val, 0.0f); }
          if constexpr (EPI == EPI_BIASR) val += bias[m0 + rr];
          if constexpr (EPI == EPI_OUT)
            val += wfb[bz * 1024 + m0 + rr] * dvv[bz * 512 + n0 + cc];
          Ch[(size_t)rr * ldc + cc] = (f16)val;
        }
  }
  (void)scale;
}

// 256x256 scores GEMM reading q,k in f32, REG-STAGED to f16 LDS (proven R14):
// f32 -> regs -> cvt_pkrtz -> ds_write_b128; 3 buffers, one __syncthreads/step.
__global__ __launch_bounds__(512, 2)
void gemm256_scores(const float* __restrict__ A, const float* __restrict__ B, f16* __restrict__ C,
                    float scale, float* __restrict__ mmarr)
{
  __shared__ __align__(16) f16 As[3][256][32];
  __shared__ __align__(16) f16 Bs[3][256][32];
  __shared__ float redm[8], redn[8];
  const int tid  = threadIdx.x;
  const int lane = tid & 63;
  const int w    = tid >> 6;           // 0..7
  const int wm   = w >> 2, wn = w & 3; // 2 x 4
  const int lin  = blockIdx.x;
  const int xcd = lin & 7, rest = lin >> 3;
  const int bj  = rest & 15;
  const int bz  = xcd + ((rest >> 4) << 3);
  const int m0 = (bj >> 2) * 256, n0 = (bj & 3) * 256;
  const float* Ab = A + (size_t)bz * 524288 + (size_t)m0 * 512;
  const float* Bb = B + (size_t)bz * 524288 + (size_t)n0 * 512;

  const int r0  = tid >> 2;
  const int sg0 = (tid & 3) ^ ((r0 >> 1) & 3);
  const size_t offG = (size_t)r0 * 512 + sg0 * 8;      // f32 offset
  f16* const dstA0 = (f16*)As + (size_t)tid * 8;       // + buf*8192
  f16* const dstB0 = (f16*)Bs + (size_t)tid * 8;

  f32x4 acc[8][4] = {};

#pragma unroll
  for (int s = 0; s < 2; ++s) {
    const int k0 = s << 5;
    float4 a0 = *(const float4*)(Ab + offG + k0);
    float4 a1 = *(const float4*)(Ab + offG + k0 + 4);
    float4 a2 = *(const float4*)(Ab + offG + k0 + 65536);
    float4 a3 = *(const float4*)(Ab + offG + k0 + 65540);
    float4 b0 = *(const float4*)(Bb + offG + k0);
    float4 b1 = *(const float4*)(Bb + offG + k0 + 4);
    float4 b2 = *(const float4*)(Bb + offG + k0 + 65536);
    float4 b3 = *(const float4*)(Bb + offG + k0 + 65540);
    *(f16x8*)(dstA0 + s * 8192)        = pack8(a0, a1);
    *(f16x8*)(dstA0 + s * 8192 + 4096) = pack8(a2, a3);
    *(f16x8*)(dstB0 + s * 8192)        = pack8(b0, b1);
    *(f16x8*)(dstB0 + s * 8192 + 4096) = pack8(b2, b3);
  }
  __syncthreads();

  const int fr = lane & 15;
  const int elemoff = (((lane >> 4) ^ ((lane >> 1) & 3)) << 3);  // f16 elements

  int cur = 0;
  for (int t = 0; t < 16; ++t) {
    float4 a0, a1, a2, a3, b0, b1, b2, b3;
    if (t + 2 < 16) {
      const int k0 = (t + 2) << 5;
      a0 = *(const float4*)(Ab + offG + k0);
      a1 = *(const float4*)(Ab + offG + k0 + 4);
      a2 = *(const float4*)(Ab + offG + k0 + 65536);
      a3 = *(const float4*)(Ab + offG + k0 + 65540);
      b0 = *(const float4*)(Bb + offG + k0);
      b1 = *(const float4*)(Bb + offG + k0 + 4);
      b2 = *(const float4*)(Bb + offG + k0 + 65536);
      b3 = *(const float4*)(Bb + offG + k0 + 65540);
    }
    f16x8 af[8], bfr[4];
#pragma unroll
    for (int m = 0; m < 8; ++m)
      af[m] = *(const f16x8*)&As[cur][wm * 128 + m * 16 + fr][elemoff];
#pragma unroll
    for (int n = 0; n < 4; ++n)
      bfr[n] = *(const f16x8*)&Bs[cur][wn * 64 + n * 16 + fr][elemoff];
    __builtin_amdgcn_s_setprio(1);
#pragma unroll
    for (int m = 0; m < 8; ++m)
#pragma unroll
      for (int n = 0; n < 4; ++n)
        acc[m][n] = __builtin_amdgcn_mfma_f32_16x16x32_f16(af[m], bfr[n], acc[m][n], 0, 0, 0);
    __builtin_amdgcn_s_setprio(0);
    if (t + 2 < 16) {
      int wb = cur + 2; if (wb >= 3) wb -= 3;
      *(f16x8*)(dstA0 + wb * 8192)        = pack8(a0, a1);
      *(f16x8*)(dstA0 + wb * 8192 + 4096) = pack8(a2, a3);
      *(f16x8*)(dstB0 + wb * 8192)        = pack8(b0, b1);
      *(f16x8*)(dstB0 + wb * 8192 + 4096) = pack8(b2, b3);
    }
    __syncthreads();
    cur = (cur + 1 == 3) ? 0 : cur + 1;
  }

  const int col_l = lane & 15;
  const int row_l = (lane >> 4) << 2;
  f16* Ch = C + (size_t)bz * 1048576 + (size_t)m0 * 1024 + n0;
  float lmax = -3.402823466e38f, lmin = 3.402823466e38f;
#pragma unroll
  for (int m = 0; m < 8; ++m)
#pragma unroll
    for (int n = 0; n < 4; ++n)
#pragma unroll
      for (int r = 0; r < 4; ++r) {
        float val = acc[m][n][r] * scale;
        lmax = fmaxf(lmax, val); lmin = fminf(lmin, val);
        Ch[(size_t)(wm * 128 + m * 16 + row_l + r) * 1024 + (wn * 64 + n * 16 + col_l)] = (f16)val;
      }
#pragma unroll
  for (int off = 32; off >= 1; off >>= 1) {
    lmax = fmaxf(lmax, __shfl_xor(lmax, off));
    lmin = fminf(lmin, __shfl_xor(lmin, off));
  }
  if (lane == 0) { redm[w] = lmax; redn[w] = lmin; }
  __syncthreads();
  if (tid == 0) {
    float gm = redm[0], gn = redn[0];
#pragma unroll
    for (int i = 1; i < 8; ++i) { gm = fmaxf(gm, redm[i]); gn = fminf(gn, redn[i]); }
    mmarr[lin] = gm; mmarr[256 + lin] = gn;
  }
}

// vpt[d][k] = sum_e Wv[d][e]*v[k][e] + bv[d].  A = Wv16 (f16), B = v (f32 direct).
// Reg-staged to f16 LDS, 128x128 tile, 4 waves, 3 buffers, one __syncthreads/step.
// (validated R15; standalone so softmax keeps its high occupancy — R16 lesson)
__global__ __launch_bounds__(256)
void gemm_vpt(const f16* __restrict__ A, const float* __restrict__ B, f16* __restrict__ C,
              const float* __restrict__ bias)
{
  __shared__ __align__(16) f16 As[3][128][32];
  __shared__ __align__(16) f16 Bs[3][128][32];
  const int tid  = threadIdx.x;
  const int lane = tid & 63;
  const int w    = tid >> 6;
  const int wm   = w >> 1, wn = w & 1;
  const int lin  = blockIdx.x;
  const int xcd = lin & 7, rest = lin >> 3;
  const int grp = rest >> 5, bj = rest & 31;
  const int bz  = xcd + (grp << 3);
  const int m0 = (bj >> 3) * 128, n0 = (bj & 7) * 128;
  const f16*   Ab = A + (size_t)m0 * 512;
  const float* Bb = B + (size_t)bz * 524288 + (size_t)n0 * 512;

  const int r0  = tid >> 2;
  const int sg0 = (tid & 3) ^ ((r0 >> 1) & 3);
  const size_t offA = (size_t)r0 * 512 + sg0 * 8;   // f16 elems
  const size_t offB = (size_t)r0 * 512 + sg0 * 8;   // f32 elems
  f16* const dstA0 = (f16*)As + (size_t)tid * 8;    // + buf*4096
  f16* const dstB0 = (f16*)Bs + (size_t)tid * 8;

  f32x4 acc[4][4] = {};

#pragma unroll
  for (int s = 0; s < 2; ++s) {
    const int k0 = s << 5;
    f16x8  a0 = *(const f16x8*)(Ab + offA + k0);
    f16x8  a1 = *(const f16x8*)(Ab + offA + k0 + 32768);
    float4 b0 = *(const float4*)(Bb + offB + k0);
    float4 b1 = *(const float4*)(Bb + offB + k0 + 4);
    float4 b2 = *(const float4*)(Bb + offB + k0 + 32768);
    float4 b3 = *(const float4*)(Bb + offB + k0 + 32772);
    *(f16x8*)(dstA0 + s * 4096)        = a0;
    *(f16x8*)(dstA0 + s * 4096 + 2048) = a1;
    *(f16x8*)(dstB0 + s * 4096)        = pack8(b0, b1);
    *(f16x8*)(dstB0 + s * 4096 + 2048) = pack8(b2, b3);
  }
  __syncthreads();

  const int fr = lane & 15;
  const int elemoff = (((lane >> 4) ^ ((lane >> 1) & 3)) << 3);

  int cur = 0;
  for (int t = 0; t < 16; ++t) {
    f16x8  a0, a1; float4 b0, b1, b2, b3;
    if (t + 2 < 16) {
      const int k0 = (t + 2) << 5;
      a0 = *(const f16x8*)(Ab + offA + k0);
      a1 = *(const f16x8*)(Ab + offA + k0 + 32768);
      b0 = *(const float4*)(Bb + offB + k0);
      b1 = *(const float4*)(Bb + offB + k0 + 4);
      b2 = *(const float4*)(Bb + offB + k0 + 32768);
      b3 = *(const float4*)(Bb + offB + k0 + 32772);
    }
    f16x8 af[4], bfr[4];
#pragma unroll
    for (int m = 0; m < 4; ++m)
      af[m] = *(const f16x8*)&As[cur][wm * 64 + m * 16 + fr][elemoff];
#pragma unroll
    for (int n = 0; n < 4; ++n)
      bfr[n] = *(const f16x8*)&Bs[cur][wn * 64 + n * 16 + fr][elemoff];
    __builtin_amdgcn_s_setprio(1);
#pragma unroll
    for (int m = 0; m < 4; ++m)
#pragma unroll
      for (int n = 0; n < 4; ++n)
        acc[m][n] = __builtin_amdgcn_mfma_f32_16x16x32_f16(af[m], bfr[n], acc[m][n], 0, 0, 0);
    __builtin_amdgcn_s_setprio(0);
    if (t + 2 < 16) {
      int wb = cur + 2; if (wb >= 3) wb -= 3;
      *(f16x8*)(dstA0 + wb * 4096)        = a0;
      *(f16x8*)(dstA0 + wb * 4096 + 2048) = a1;
      *(f16x8*)(dstB0 + wb * 4096)        = pack8(b0, b1);
      *(f16x8*)(dstB0 + wb * 4096 + 2048) = pack8(b2, b3);
    }
    __syncthreads();
    cur = (cur + 1 == 3) ? 0 : cur + 1;
  }

  const int col_l = lane & 15;
  const int row_l = (lane >> 4) << 2;
  f16* Ch = C + (size_t)bz * 524288 + (size_t)m0 * 1024 + n0;
#pragma unroll
  for (int m = 0; m < 4; ++m)
#pragma unroll
    for (int n = 0; n < 4; ++n)
#pragma unroll
      for (int r = 0; r < 4; ++r) {
        const int rr = wm * 64 + m * 16 + row_l + r;
        const int cc = wn * 64 + n * 16 + col_l;
        Ch[(size_t)rr * 1024 + cc] = (f16)(acc[m][n][r] + bias[m0 + rr]);
      }
}

// merged front work: [0,640) weight converts; [640,2688) dv FC; [2688] mask sniff
__global__ __launch_bounds__(256)
void front_k(const float* __restrict__ wv, const float* __restrict__ w1,
             const float* __restrict__ w2,
             f16* __restrict__ owv, f16* __restrict__ ow1, f16* __restrict__ ow2,
             const float* __restrict__ uq, const float* __restrict__ Wf,
             const float* __restrict__ bfv, float* __restrict__ dv,
             const unsigned char* __restrict__ mask, unsigned* __restrict__ mm)
{
  const int blk = blockIdx.x;
  if (blk < 640) {
    int i = blk * 256 + threadIdx.x;   // 0..163839
    const float* src; f16* dst; int j;
    if (i < 65536)       { src = wv; dst = owv; j = i; }
    else if (i < 131072) { src = w1; dst = ow1; j = i - 65536; }
    else                 { src = w2; dst = ow2; j = i - 131072; }
    float4 x = *(const float4*)(src + (size_t)j * 4);
    f16x4 o = { (f16)x.x, (f16)x.y, (f16)x.z, (f16)x.w };
    *(f16x4*)(dst + (size_t)j * 4) = o;
  } else if (blk < 2688) {
    const int gw   = ((blk - 640) * 256 + threadIdx.x) >> 6;  // 0..8191
    const int lane = threadIdx.x & 63;
    const int b = gw >> 9, j = gw & 511;
    const float* x  = uq + (size_t)b * 512;
    const float* wr = Wf + (size_t)j * 512;
    const int o = lane * 8;
    float4 x0 = *(const float4*)(x + o),  x1 = *(const float4*)(x + o + 4);
    float4 w0 = *(const float4*)(wr + o), w1v = *(const float4*)(wr + o + 4);
    float s = x0.x*w0.x + x0.y*w0.y + x0.z*w0.z + x0.w*w0.w
            + x1.x*w1v.x + x1.y*w1v.y + x1.z*w1v.z + x1.w*w1v.w;
#pragma unroll
    for (int off = 32; off >= 1; off >>= 1) s += __shfl_xor(s, off);
    if (lane == 0) dv[gw] = s + bfv[j];
  } else {
    __shared__ int redc[256];
    int c = 0;
    for (int i = threadIdx.x; i < 16384; i += 256) c += (mask[i] != 0) ? 1 : 0;
    redc[threadIdx.x] = c;
    __syncthreads();
    for (int s = 128; s > 0; s >>= 1) {
      if (threadIdx.x < s) redc[threadIdx.x] += redc[threadIdx.x + s];
      __syncthreads();
    }
    if (threadIdx.x == 0) mm[0] = (unsigned)redc[0];
  }
}

// row softmax; each block re-reduces mmarr -> fb locally (identical sequence per
// block -> bitwise-identical fb; deletes the 1-block reduce_mm bubble). Tiny LDS
// so occupancy stays high (R16 lesson: do NOT merge with the fat-LDS vpt GEMM).
__global__ __launch_bounds__(256)
void softmax_rows(const f16* __restrict__ scores, const void* __restrict__ maskp,
                  const float* __restrict__ fallback, const float* __restrict__ mmarr,
                  const unsigned* __restrict__ mm,
                  f16* __restrict__ Wt, float* __restrict__ wfb)
{
  __shared__ float red[8];
  const int row  = blockIdx.x;
  const int b    = row >> 10;
  const int tid  = threadIdx.x;
  const int lane = tid & 63, w = tid >> 6;

  // fb reduction (mmarr is 2KB, L2-resident broadcast)
  float mx0 = mmarr[tid];
  float mn0 = mmarr[256 + tid];
#pragma unroll
  for (int off = 32; off >= 1; off >>= 1) {
    mx0 = fmaxf(mx0, __shfl_xor(mx0, off));
    mn0 = fminf(mn0, __shfl_xor(mn0, off));
  }
  if (lane == 0) { red[w] = mx0; red[4 + w] = mn0; }
  __syncthreads();
  const float gmax = fmaxf(fmaxf(red[0], red[1]), fmaxf(red[2], red[3]));
  const float gmin = fminf(fminf(red[4], red[5]), fminf(red[6], red[7]));
  const float fb = 0.99f * fallback[0] + 0.005f * (gmax + gmin);
  const unsigned mode = (mm[0] > 5000u) ? 1u : 0u;
  __syncthreads();

  const f16* s = scores + (size_t)row * 1024;
  const int k0 = tid * 4;
  f16x4 sv = *(const f16x4*)(s + k0);
  float x[4];
  if (mode) {
    const unsigned char* m8 = (const unsigned char*)maskp + b * 1024 + k0;
    x[0] = m8[0] ? -1e9f : (float)sv[0];  x[1] = m8[1] ? -1e9f : (float)sv[1];
    x[2] = m8[2] ? -1e9f : (float)sv[2];  x[3] = m8[3] ? -1e9f : (float)sv[3];
  } else {
    const int* mi = (const int*)maskp + b * 1024 + k0;
    x[0] = mi[0] ? -1e9f : (float)sv[0];  x[1] = mi[1] ? -1e9f : (float)sv[1];
    x[2] = mi[2] ? -1e9f : (float)sv[2];  x[3] = mi[3] ? -1e9f : (float)sv[3];
  }
  float mx = fmaxf(fmaxf(x[0], x[1]), fmaxf(x[2], x[3]));
#pragma unroll
  for (int off = 32; off >= 1; off >>= 1) mx = fmaxf(mx, __shfl_xor(mx, off));
  if (lane == 0) red[w] = mx;
  __syncthreads();
  mx = fmaxf(fmaxf(fmaxf(red[0], red[1]), fmaxf(red[2], red[3])), fb);
  float e0 = expf(x[0] - mx), e1 = expf(x[1] - mx), e2 = expf(x[2] - mx), e3 = expf(x[3] - mx);
  float sum = (e0 + e1) + (e2 + e3);
#pragma unroll
  for (int off = 32; off >= 1; off >>= 1) sum += __shfl_xor(sum, off);
  if (lane == 0) red[4 + w] = sum;
  __syncthreads();
  float efb = expf(fb - mx);
  float Z = ((red[4] + red[5]) + (red[6] + red[7])) + efb;
  float inv = 1.0f / Z;
  f16x4 o = { (f16)(e0 * inv), (f16)(e1 * inv), (f16)(e2 * inv), (f16)(e3 * inv) };
  *(f16x4*)&Wt[(size_t)row * 1024 + k0] = o;
  if (tid == 0) wfb[row] = efb * inv;
}

// wave-per-output FC: Y[b,j] = act(X[b,:] . W[j,:] + bias[j])
template<int IN, int ACT>
__global__ __launch_bounds__(256)
void fc_wave(const float* __restrict__ X, const float* __restrict__ W,
             const float* __restrict__ bias, float* __restrict__ Y, int OutN)
{
  const int gw   = (blockIdx.x * 256 + threadIdx.x) >> 6;
  const int lane = threadIdx.x & 63;
  const int b = gw / OutN, j = gw - b * OutN;
  const float* x  = X + (size_t)b * IN;
  const float* wr = W + (size_t)j * IN;
  float s = 0.f;
  if constexpr (IN == 512) {
    const int o = lane * 8;
    float4 x0 = *(const float4*)(x + o),  x1 = *(const float4*)(x + o + 4);
    float4 w0 = *(const float4*)(wr + o), w1 = *(const float4*)(wr + o + 4);
    s = x0.x*w0.x + x0.y*w0.y + x0.z*w0.z + x0.w*w0.w
      + x1.x*w1.x + x1.y*w1.y + x1.z*w1.z + x1.w*w1.w;
  } else {
    const int o = lane * 4;
    float4 x0 = *(const float4*)(x + o);
    float4 w0 = *(const float4*)(wr + o);
    s = x0.x*w0.x + x0.y*w0.y + x0.z*w0.z + x0.w*w0.w;
  }
#pragma unroll
  for (int off = 32; off >= 1; off >>= 1) s += __shfl_xor(s, off);
  if (lane == 0) {
    float val = s + bias[ACT == 2 ? 0 : j];
    if constexpr (ACT == 1) val = fmaxf(val, 0.f);
    if constexpr (ACT == 2) val = tanhf(val);
    Y[gw] = val;
  }
}

__global__ __launch_bounds__(256)
void y_kernel(const f16* __restrict__ h2, const float* __restrict__ W3,
              const float* __restrict__ b3, float* __restrict__ outp)
{
  int row = blockIdx.x * 16 + (threadIdx.x >> 4);
  int l   = threadIdx.x & 15;
  const f16* h = h2 + (size_t)row * 256 + l * 16;
  float s = 0.f;
#pragma unroll
  for (int j = 0; j < 16; ++j) s += (float)h[j] * W3[l * 16 + j];
#pragma unroll
  for (int off = 1; off < 16; off <<= 1) s += __shfl_xor(s, off);
  if (l == 0) outp[row] = tanhf(s + b3[0]);
}

extern "C" void kernel_launch(void* const* d_in, const int* in_sizes, int n_in,
                              void* d_out, int out_size, void* d_ws, size_t ws_size,
                              hipStream_t stream) {
  const float* uq       = (const float*)d_in[0];
  const float* q        = (const float*)d_in[1];
  const float* kk       = (const float*)d_in[2];
  const float* v        = (const float*)d_in[3];
  const void*  mask     = d_in[4];
  const float* fallback = (const float*)d_in[5];
  const float* Wv = (const float*)d_in[6];
  const float* bv = (const float*)d_in[7];
  const float* Wf = (const float*)d_in[8];
  const float* bf = (const float*)d_in[9];
  const float* W1 = (const float*)d_in[10];
  const float* b1 = (const float*)d_in[11];
  const float* W2 = (const float*)d_in[12];
  const float* b2 = (const float*)d_in[13];
  const float* W3 = (const float*)d_in[14];
  const float* b3 = (const float*)d_in[15];
  float* outp = (float*)d_out;

  char* ws = (char*)d_ws;
  const size_t MB = 1ull << 20;
  f16*  scores = (f16*)ws;
  f16*  h1b  = (f16*)ws;
  f16*  h2b  = (f16*)(ws + 16 * MB);
  f16*  vpt  = (f16*)(ws + 32 * MB);
  f16*  outb = (f16*)(ws + 48 * MB);
  f16*  wts  = (f16*)(ws + 64 * MB);
  char* cst  = ws + 112 * MB;
  f16*  Wv16 = (f16*)(cst);
  f16*  W116 = (f16*)(cst + 512 * 1024);
  f16*  W216 = (f16*)(cst + 1024 * 1024);
  float* dv   = (float*)(cst + 1280 * 1024);
  float* wfb  = (float*)(cst + 1312 * 1024);
  float* h1d  = (float*)(cst + 1376 * 1024);
  float* h2d  = (float*)(cst + 1408 * 1024);
  unsigned* mm = (unsigned*)(cst + 1424 * 1024);
  float* mmarr = (float*)(cst + 1432 * 1024);   // 2 * 256 floats

  // weight converts + dv FC + mask sniff
  front_k<<<2689, 256, 0, stream>>>(Wv, W1, W2, Wv16, W116, W216,
                                    uq, Wf, bf, dv,
                                    (const unsigned char*)mask, mm);

  // scores = q @ k^T / sqrt(512) -> f16, q/k read as f32, reg-staged to f16 LDS
  gemm256_scores<<<256, 512, 0, stream>>>(q, kk, scores, 0.04419417382415922f, mmarr);

  // row softmax (fb reduced per block; reduce_mm dispatch eliminated)
  softmax_rows<<<16384, 256, 0, stream>>>(scores, mask, fallback, mmarr, mm, wts, wfb);

  // vpt[d][k] = sum_e Wv[d][e] v[k][e] + bv[d]  (v read f32 directly)
  gemm_vpt<<<512, 256, 0, stream>>>(Wv16, v, vpt, bv);

  // out = weights @ vp + wfb*dv
  gemm_bt<EPI_OUT, true><<<512, 256, 0, stream>>>(
      wts, vpt, outb, 1024, 1024, 512, 1024,
      1048576LL, 524288LL, 524288LL,
      nullptr, 1.f, wfb, dv, 4, 32);

  // h1 = relu(out @ W1^T + b1)
  gemm_bt<EPI_RELU, false><<<512, 256, 0, stream>>>(
      outb, W116, h1b, 512, 512, 512, 512, 0LL, 0LL, 0LL,
      b1, 1.f, nullptr, nullptr, 4, 512);

  // h2 = relu(h1 @ W2^T + b2)
  gemm_bt<EPI_RELU, false><<<256, 256, 0, stream>>>(
      h1b, W216, h2b, 512, 512, 256, 512, 0LL, 0LL, 0LL,
      b2, 1.f, nullptr, nullptr, 2, 256);

  y_kernel<<<1024, 256, 0, stream>>>(h2b, W3, b3, outp);

  // default-values scorer branch (f32, wave-per-output)
  fc_wave<512, 1><<<2048, 256, 0, stream>>>(dv, W1, b1, h1d, 512);
  fc_wave<512, 1><<<1024, 256, 0, stream>>>(h1d, W2, b2, h2d, 256);
  fc_wave<256, 2><<<4, 256, 0, stream>>>(h2d, W3, b3, outp + 16384, 1);

  (void)in_sizes; (void)n_in; (void)out_size; (void)ws_size;
}

// Round 18
// 160.506 us; speedup vs baseline: 1.2181x; 1.0052x over previous
//
#include <hip/hip_runtime.h>

typedef _Float16 f16;
typedef f16  f16x8 __attribute__((ext_vector_type(8)));
typedef f16  f16x4 __attribute__((ext_vector_type(4)));
typedef __fp16 fp16x2 __attribute__((ext_vector_type(2)));
typedef float f32x4 __attribute__((ext_vector_type(4)));

__device__ __forceinline__ void gld_lds16(const f16* g, void* l) {
  __builtin_amdgcn_global_load_lds((const __attribute__((address_space(1))) void*)g,
                                   (__attribute__((address_space(3))) void*)l,
                                   16, 0, 0);
}

// pack 8 f32 -> f16x8 via v_cvt_pkrtz (RTZ)
__device__ __forceinline__ f16x8 pack8(float4 a, float4 b) {
  union { f16x8 v; fp16x2 h[4]; } u;
  u.h[0] = __builtin_amdgcn_cvt_pkrtz(a.x, a.y);
  u.h[1] = __builtin_amdgcn_cvt_pkrtz(a.z, a.w);
  u.h[2] = __builtin_amdgcn_cvt_pkrtz(b.x, b.y);
  u.h[3] = __builtin_amdgcn_cvt_pkrtz(b.z, b.w);
  return u.v;
}

enum { EPI_SCORES = 0, EPI_RELU = 2, EPI_OUT = 3, EPI_BIASR = 4 };

// C[M,N] = A[M,K] @ B[N,K]^T, 128x128 tile, BK=32, 4 waves (2x2), 16x16x32 f16 MFMA.
// 4-stage LDS pipeline, counted vmcnt drain 8->4->0, raw s_barrier, swizzled LDS.
template<int EPI, bool XMAP>
__global__ __launch_bounds__(256)
void gemm_bt(const f16* __restrict__ A, const f16* __restrict__ B, void* __restrict__ C,
             int lda, int ldb, int ldc, int K,
             long long sA, long long sB, long long sC,
             const float* __restrict__ bias, float scale,
             const float* __restrict__ wfb, const float* __restrict__ dvv,
             int nx, int nbz)
{
  __shared__ __align__(16) f16 As[4][128][32];
  __shared__ __align__(16) f16 Bs[4][128][32];
  const int tid  = threadIdx.x;
  const int lane = tid & 63;
  const int w    = tid >> 6;
  const int wm   = w >> 1, wn = w & 1;

  const int lin = blockIdx.x;
  int bz, bj;
  if constexpr (XMAP) {
    const int xcd = lin & 7, rest = lin >> 3;
    const int grp = rest / nbz;
    bj = rest - grp * nbz;
    bz = xcd + (grp << 3);
  } else {
    bz = lin / nbz; bj = lin - bz * nbz;
  }
  const int m0 = (bj / nx) * 128, n0 = (bj % nx) * 128;
  const f16* Ab = A + (size_t)bz * sA + (size_t)m0 * lda;
  const f16* Bb = B + (size_t)bz * sB + (size_t)n0 * ldb;

  f32x4 acc[4][4] = {};
  const int nsteps = K >> 5;

#define STAGE(bufb, ks)                                                              \
  {                                                                                  \
    const int k0_ = (ks) << 5;                                                       \
    _Pragma("unroll")                                                                \
    for (int i = 0; i < 2; ++i) {                                                    \
      const int ci = i * 256 + tid;                                                  \
      const int r  = ci >> 2;                                                        \
      const int sg = (ci & 3) ^ ((r >> 1) & 3);                                      \
      gld_lds16(Ab + (size_t)r * lda + k0_ + sg * 8,                                 \
                (char*)As + (bufb) + (size_t)(i * 256 + w * 64) * 16);               \
      gld_lds16(Bb + (size_t)r * ldb + k0_ + sg * 8,                                 \
                (char*)Bs + (bufb) + (size_t)(i * 256 + w * 64) * 16);               \
    }                                                                                \
  }

  STAGE(0, 0)
  if (1 < nsteps) STAGE(8192, 1)
  if (2 < nsteps) STAGE(16384, 2)

  const int elemoff = (((lane >> 4) ^ ((lane >> 1) & 3)) << 3);

  int cur = 0;
  for (int t = 0; t < nsteps; ++t) {
    if (t + 2 < nsteps)      asm volatile("s_waitcnt vmcnt(8)" ::: "memory");
    else if (t + 1 < nsteps) asm volatile("s_waitcnt vmcnt(4)" ::: "memory");
    else                     asm volatile("s_waitcnt vmcnt(0)" ::: "memory");
    __builtin_amdgcn_s_barrier();
    __builtin_amdgcn_sched_barrier(0);
    if (t + 3 < nsteps) STAGE(((cur + 3) & 3) * 8192, t + 3)
    f16x8 af[4], bfr[4];
#pragma unroll
    for (int m = 0; m < 4; ++m)
      af[m] = *(const f16x8*)&As[cur][wm * 64 + m * 16 + (lane & 15)][elemoff];
#pragma unroll
    for (int n = 0; n < 4; ++n)
      bfr[n] = *(const f16x8*)&Bs[cur][wn * 64 + n * 16 + (lane & 15)][elemoff];
    __builtin_amdgcn_s_setprio(1);
#pragma unroll
    for (int m = 0; m < 4; ++m)
#pragma unroll
      for (int n = 0; n < 4; ++n)
        acc[m][n] = __builtin_amdgcn_mfma_f32_16x16x32_f16(af[m], bfr[n], acc[m][n], 0, 0, 0);
    __builtin_amdgcn_s_setprio(0);
    cur = (cur + 1) & 3;
  }
#undef STAGE

  const int col_l = lane & 15;
  const int row_l = (lane >> 4) << 2;

  {
    f16* Ch = (f16*)C + (size_t)bz * sC + (size_t)m0 * ldc + n0;
#pragma unroll
    for (int m = 0; m < 4; ++m)
#pragma unroll
      for (int n = 0; n < 4; ++n)
#pragma unroll
        for (int r = 0; r < 4; ++r) {
          const int rr = wm * 64 + m * 16 + row_l + r;
          const int cc = wn * 64 + n * 16 + col_l;
          float val = acc[m][n][r];
          if constexpr (EPI == EPI_RELU) { val += bias[n0 + cc]; val = fmaxf(val, 0.0f); }
          if constexpr (EPI == EPI_BIASR) val += bias[m0 + rr];
          if constexpr (EPI == EPI_OUT)
            val += wfb[bz * 1024 + m0 + rr] * dvv[bz * 512 + n0 + cc];
          Ch[(size_t)rr * ldc + cc] = (f16)val;
        }
  }
  (void)scale;
}

// 256x256 scores GEMM, f32 q/k reg-staged to f16 LDS. R18: T3/T4 step reorder —
// {ds_read frags; pack8+ds_write held regs (stage t+2); issue loads stage t+3;
// MFMA; lgkmcnt(0)+RAW s_barrier (no vmcnt drain)}. Loads stay in flight a full
// step across the barrier; __syncthreads (vmcnt0 drain) eliminated from the loop.
__global__ __launch_bounds__(512, 2)
void gemm256_scores(const float* __restrict__ A, const float* __restrict__ B, f16* __restrict__ C,
                    float scale, float* __restrict__ mmarr)
{
  __shared__ __align__(16) f16 As[3][256][32];
  __shared__ __align__(16) f16 Bs[3][256][32];
  __shared__ float redm[8], redn[8];
  const int tid  = threadIdx.x;
  const int lane = tid & 63;
  const int w    = tid >> 6;           // 0..7
  const int wm   = w >> 2, wn = w & 3; // 2 x 4
  const int lin  = blockIdx.x;
  const int xcd = lin & 7, rest = lin >> 3;
  const int bj  = rest & 15;
  const int bz  = xcd + ((rest >> 4) << 3);
  const int m0 = (bj >> 2) * 256, n0 = (bj & 3) * 256;
  const float* Ab = A + (size_t)bz * 524288 + (size_t)m0 * 512;
  const float* Bb = B + (size_t)bz * 524288 + (size_t)n0 * 512;

  const int r0  = tid >> 2;
  const int sg0 = (tid & 3) ^ ((r0 >> 1) & 3);
  const size_t offG = (size_t)r0 * 512 + sg0 * 8;      // f32 offset
  f16* const dstA0 = (f16*)As + (size_t)tid * 8;       // + buf*8192
  f16* const dstB0 = (f16*)Bs + (size_t)tid * 8;

  f32x4 acc[8][4] = {};

  // prologue: stages 0,1 synchronous into buf0,1
#pragma unroll
  for (int s = 0; s < 2; ++s) {
    const int k0 = s << 5;
    float4 a0 = *(const float4*)(Ab + offG + k0);
    float4 a1 = *(const float4*)(Ab + offG + k0 + 4);
    float4 a2 = *(const float4*)(Ab + offG + k0 + 65536);
    float4 a3 = *(const float4*)(Ab + offG + k0 + 65540);
    float4 b0 = *(const float4*)(Bb + offG + k0);
    float4 b1 = *(const float4*)(Bb + offG + k0 + 4);
    float4 b2 = *(const float4*)(Bb + offG + k0 + 65536);
    float4 b3 = *(const float4*)(Bb + offG + k0 + 65540);
    *(f16x8*)(dstA0 + s * 8192)        = pack8(a0, a1);
    *(f16x8*)(dstA0 + s * 8192 + 4096) = pack8(a2, a3);
    *(f16x8*)(dstB0 + s * 8192)        = pack8(b0, b1);
    *(f16x8*)(dstB0 + s * 8192 + 4096) = pack8(b2, b3);
  }
  // issue loads for stage 2 into held regs
  float4 ha0, ha1, ha2, ha3, hb0, hb1, hb2, hb3;
  {
    const int k0 = 2 << 5;
    ha0 = *(const float4*)(Ab + offG + k0);
    ha1 = *(const float4*)(Ab + offG + k0 + 4);
    ha2 = *(const float4*)(Ab + offG + k0 + 65536);
    ha3 = *(const float4*)(Ab + offG + k0 + 65540);
    hb0 = *(const float4*)(Bb + offG + k0);
    hb1 = *(const float4*)(Bb + offG + k0 + 4);
    hb2 = *(const float4*)(Bb + offG + k0 + 65536);
    hb3 = *(const float4*)(Bb + offG + k0 + 65540);
  }
  __syncthreads();

  const int fr = lane & 15;
  const int elemoff = (((lane >> 4) ^ ((lane >> 1) & 3)) << 3);  // f16 elements

  int cur = 0;
  for (int t = 0; t < 16; ++t) {
    // phase 1: fragment reads from buf[cur]
    f16x8 af[8], bfr[4];
#pragma unroll
    for (int m = 0; m < 8; ++m)
      af[m] = *(const f16x8*)&As[cur][wm * 128 + m * 16 + fr][elemoff];
#pragma unroll
    for (int n = 0; n < 4; ++n)
      bfr[n] = *(const f16x8*)&Bs[cur][wn * 64 + n * 16 + fr][elemoff];
    // phase 2: publish stage t+2 (held regs, loaded one step earlier)
    if (t + 2 < 16) {
      int wb = cur + 2; if (wb >= 3) wb -= 3;
      *(f16x8*)(dstA0 + wb * 8192)        = pack8(ha0, ha1);
      *(f16x8*)(dstA0 + wb * 8192 + 4096) = pack8(ha2, ha3);
      *(f16x8*)(dstB0 + wb * 8192)        = pack8(hb0, hb1);
      *(f16x8*)(dstB0 + wb * 8192 + 4096) = pack8(hb2, hb3);
    }
    // phase 3: issue loads for stage t+3 (consumed in phase 2 of step t+1)
    if (t + 3 < 16) {
      const int k0 = (t + 3) << 5;
      ha0 = *(const float4*)(Ab + offG + k0);
      ha1 = *(const float4*)(Ab + offG + k0 + 4);
      ha2 = *(const float4*)(Ab + offG + k0 + 65536);
      ha3 = *(const float4*)(Ab + offG + k0 + 65540);
      hb0 = *(const float4*)(Bb + offG + k0);
      hb1 = *(const float4*)(Bb + offG + k0 + 4);
      hb2 = *(const float4*)(Bb + offG + k0 + 65536);
      hb3 = *(const float4*)(Bb + offG + k0 + 65540);
    }
    // phase 4: MFMA (compiler inserts lgkm waits for af/bfr)
    __builtin_amdgcn_s_setprio(1);
#pragma unroll
    for (int m = 0; m < 8; ++m)
#pragma unroll
      for (int n = 0; n < 4; ++n)
        acc[m][n] = __builtin_amdgcn_mfma_f32_16x16x32_f16(af[m], bfr[n], acc[m][n], 0, 0, 0);
    __builtin_amdgcn_s_setprio(0);
    // phase 5: publish ds_writes, raw barrier WITHOUT vmcnt drain
    asm volatile("s_waitcnt lgkmcnt(0)" ::: "memory");
    __builtin_amdgcn_sched_barrier(0);
    __builtin_amdgcn_s_barrier();
    cur = (cur + 1 == 3) ? 0 : cur + 1;
  }

  const int col_l = lane & 15;
  const int row_l = (lane >> 4) << 2;
  f16* Ch = C + (size_t)bz * 1048576 + (size_t)m0 * 1024 + n0;
  float lmax = -3.402823466e38f, lmin = 3.402823466e38f;
#pragma unroll
  for (int m = 0; m < 8; ++m)
#pragma unroll
    for (int n = 0; n < 4; ++n)
#pragma unroll
      for (int r = 0; r < 4; ++r) {
        float val = acc[m][n][r] * scale;
        lmax = fmaxf(lmax, val); lmin = fminf(lmin, val);
        Ch[(size_t)(wm * 128 + m * 16 + row_l + r) * 1024 + (wn * 64 + n * 16 + col_l)] = (f16)val;
      }
#pragma unroll
  for (int off = 32; off >= 1; off >>= 1) {
    lmax = fmaxf(lmax, __shfl_xor(lmax, off));
    lmin = fminf(lmin, __shfl_xor(lmin, off));
  }
  if (lane == 0) { redm[w] = lmax; redn[w] = lmin; }
  __syncthreads();
  if (tid == 0) {
    float gm = redm[0], gn = redn[0];
#pragma unroll
    for (int i = 1; i < 8; ++i) { gm = fmaxf(gm, redm[i]); gn = fminf(gn, redn[i]); }
    mmarr[lin] = gm; mmarr[256 + lin] = gn;
  }
}

// vpt[d][k] = sum_e Wv[d][e]*v[k][e] + bv[d].  (validated R15, standalone per R16 lesson)
__global__ __launch_bounds__(256)
void gemm_vpt(const f16* __restrict__ A, const float* __restrict__ B, f16* __restrict__ C,
              const float* __restrict__ bias)
{
  __shared__ __align__(16) f16 As[3][128][32];
  __shared__ __align__(16) f16 Bs[3][128][32];
  const int tid  = threadIdx.x;
  const int lane = tid & 63;
  const int w    = tid >> 6;
  const int wm   = w >> 1, wn = w & 1;
  const int lin  = blockIdx.x;
  const int xcd = lin & 7, rest = lin >> 3;
  const int grp = rest >> 5, bj = rest & 31;
  const int bz  = xcd + (grp << 3);
  const int m0 = (bj >> 3) * 128, n0 = (bj & 7) * 128;
  const f16*   Ab = A + (size_t)m0 * 512;
  const float* Bb = B + (size_t)bz * 524288 + (size_t)n0 * 512;

  const int r0  = tid >> 2;
  const int sg0 = (tid & 3) ^ ((r0 >> 1) & 3);
  const size_t offA = (size_t)r0 * 512 + sg0 * 8;   // f16 elems
  const size_t offB = (size_t)r0 * 512 + sg0 * 8;   // f32 elems
  f16* const dstA0 = (f16*)As + (size_t)tid * 8;    // + buf*4096
  f16* const dstB0 = (f16*)Bs + (size_t)tid * 8;

  f32x4 acc[4][4] = {};

#pragma unroll
  for (int s = 0; s < 2; ++s) {
    const int k0 = s << 5;
    f16x8  a0 = *(const f16x8*)(Ab + offA + k0);
    f16x8  a1 = *(const f16x8*)(Ab + offA + k0 + 32768);
    float4 b0 = *(const float4*)(Bb + offB + k0);
    float4 b1 = *(const float4*)(Bb + offB + k0 + 4);
    float4 b2 = *(const float4*)(Bb + offB + k0 + 32768);
    float4 b3 = *(const float4*)(Bb + offB + k0 + 32772);
    *(f16x8*)(dstA0 + s * 4096)        = a0;
    *(f16x8*)(dstA0 + s * 4096 + 2048) = a1;
    *(f16x8*)(dstB0 + s * 4096)        = pack8(b0, b1);
    *(f16x8*)(dstB0 + s * 4096 + 2048) = pack8(b2, b3);
  }
  __syncthreads();

  const int fr = lane & 15;
  const int elemoff = (((lane >> 4) ^ ((lane >> 1) & 3)) << 3);

  int cur = 0;
  for (int t = 0; t < 16; ++t) {
    f16x8  a0, a1; float4 b0, b1, b2, b3;
    if (t + 2 < 16) {
      const int k0 = (t + 2) << 5;
      a0 = *(const f16x8*)(Ab + offA + k0);
      a1 = *(const f16x8*)(Ab + offA + k0 + 32768);
      b0 = *(const float4*)(Bb + offB + k0);
      b1 = *(const float4*)(Bb + offB + k0 + 4);
      b2 = *(const float4*)(Bb + offB + k0 + 32768);
      b3 = *(const float4*)(Bb + offB + k0 + 32772);
    }
    f16x8 af[4], bfr[4];
#pragma unroll
    for (int m = 0; m < 4; ++m)
      af[m] = *(const f16x8*)&As[cur][wm * 64 + m * 16 + fr][elemoff];
#pragma unroll
    for (int n = 0; n < 4; ++n)
      bfr[n] = *(const f16x8*)&Bs[cur][wn * 64 + n * 16 + fr][elemoff];
    __builtin_amdgcn_s_setprio(1);
#pragma unroll
    for (int m = 0; m < 4; ++m)
#pragma unroll
      for (int n = 0; n < 4; ++n)
        acc[m][n] = __builtin_amdgcn_mfma_f32_16x16x32_f16(af[m], bfr[n], acc[m][n], 0, 0, 0);
    __builtin_amdgcn_s_setprio(0);
    if (t + 2 < 16) {
      int wb = cur + 2; if (wb >= 3) wb -= 3;
      *(f16x8*)(dstA0 + wb * 4096)        = a0;
      *(f16x8*)(dstA0 + wb * 4096 + 2048) = a1;
      *(f16x8*)(dstB0 + wb * 4096)        = pack8(b0, b1);
      *(f16x8*)(dstB0 + wb * 4096 + 2048) = pack8(b2, b3);
    }
    __syncthreads();
    cur = (cur + 1 == 3) ? 0 : cur + 1;
  }

  const int col_l = lane & 15;
  const int row_l = (lane >> 4) << 2;
  f16* Ch = C + (size_t)bz * 524288 + (size_t)m0 * 1024 + n0;
#pragma unroll
  for (int m = 0; m < 4; ++m)
#pragma unroll
    for (int n = 0; n < 4; ++n)
#pragma unroll
      for (int r = 0; r < 4; ++r) {
        const int rr = wm * 64 + m * 16 + row_l + r;
        const int cc = wn * 64 + n * 16 + col_l;
        Ch[(size_t)rr * 1024 + cc] = (f16)(acc[m][n][r] + bias[m0 + rr]);
      }
}

// merged front work: [0,640) weight converts; [640,2688) dv FC; [2688] mask sniff
__global__ __launch_bounds__(256)
void front_k(const float* __restrict__ wv, const float* __restrict__ w1,
             const float* __restrict__ w2,
             f16* __restrict__ owv, f16* __restrict__ ow1, f16* __restrict__ ow2,
             const float* __restrict__ uq, const float* __restrict__ Wf,
             const float* __restrict__ bfv, float* __restrict__ dv,
             const unsigned char* __restrict__ mask, unsigned* __restrict__ mm)
{
  const int blk = blockIdx.x;
  if (blk < 640) {
    int i = blk * 256 + threadIdx.x;   // 0..163839
    const float* src; f16* dst; int j;
    if (i < 65536)       { src = wv; dst = owv; j = i; }
    else if (i < 131072) { src = w1; dst = ow1; j = i - 65536; }
    else                 { src = w2; dst = ow2; j = i - 131072; }
    float4 x = *(const float4*)(src + (size_t)j * 4);
    f16x4 o = { (f16)x.x, (f16)x.y, (f16)x.z, (f16)x.w };
    *(f16x4*)(dst + (size_t)j * 4) = o;
  } else if (blk < 2688) {
    const int gw   = ((blk - 640) * 256 + threadIdx.x) >> 6;  // 0..8191
    const int lane = threadIdx.x & 63;
    const int b = gw >> 9, j = gw & 511;
    const float* x  = uq + (size_t)b * 512;
    const float* wr = Wf + (size_t)j * 512;
    const int o = lane * 8;
    float4 x0 = *(const float4*)(x + o),  x1 = *(const float4*)(x + o + 4);
    float4 w0 = *(const float4*)(wr + o), w1v = *(const float4*)(wr + o + 4);
    float s = x0.x*w0.x + x0.y*w0.y + x0.z*w0.z + x0.w*w0.w
            + x1.x*w1v.x + x1.y*w1v.y + x1.z*w1v.z + x1.w*w1v.w;
#pragma unroll
    for (int off = 32; off >= 1; off >>= 1) s += __shfl_xor(s, off);
    if (lane == 0) dv[gw] = s + bfv[j];
  } else {
    __shared__ int redc[256];
    int c = 0;
    for (int i = threadIdx.x; i < 16384; i += 256) c += (mask[i] != 0) ? 1 : 0;
    redc[threadIdx.x] = c;
    __syncthreads();
    for (int s = 128; s > 0; s >>= 1) {
      if (threadIdx.x < s) redc[threadIdx.x] += redc[threadIdx.x + s];
      __syncthreads();
    }
    if (threadIdx.x == 0) mm[0] = (unsigned)redc[0];
  }
}

// row softmax; each block re-reduces mmarr -> fb locally (bitwise-identical per block)
__global__ __launch_bounds__(256)
void softmax_rows(const f16* __restrict__ scores, const void* __restrict__ maskp,
                  const float* __restrict__ fallback, const float* __restrict__ mmarr,
                  const unsigned* __restrict__ mm,
                  f16* __restrict__ Wt, float* __restrict__ wfb)
{
  __shared__ float red[8];
  const int row  = blockIdx.x;
  const int b    = row >> 10;
  const int tid  = threadIdx.x;
  const int lane = tid & 63, w = tid >> 6;

  float mx0 = mmarr[tid];
  float mn0 = mmarr[256 + tid];
#pragma unroll
  for (int off = 32; off >= 1; off >>= 1) {
    mx0 = fmaxf(mx0, __shfl_xor(mx0, off));
    mn0 = fminf(mn0, __shfl_xor(mn0, off));
  }
  if (lane == 0) { red[w] = mx0; red[4 + w] = mn0; }
  __syncthreads();
  const float gmax = fmaxf(fmaxf(red[0], red[1]), fmaxf(red[2], red[3]));
  const float gmin = fminf(fminf(red[4], red[5]), fminf(red[6], red[7]));
  const float fb = 0.99f * fallback[0] + 0.005f * (gmax + gmin);
  const unsigned mode = (mm[0] > 5000u) ? 1u : 0u;
  __syncthreads();

  const f16* s = scores + (size_t)row * 1024;
  const int k0 = tid * 4;
  f16x4 sv = *(const f16x4*)(s + k0);
  float x[4];
  if (mode) {
    const unsigned char* m8 = (const unsigned char*)maskp + b * 1024 + k0;
    x[0] = m8[0] ? -1e9f : (float)sv[0];  x[1] = m8[1] ? -1e9f : (float)sv[1];
    x[2] = m8[2] ? -1e9f : (float)sv[2];  x[3] = m8[3] ? -1e9f : (float)sv[3];
  } else {
    const int* mi = (const int*)maskp + b * 1024 + k0;
    x[0] = mi[0] ? -1e9f : (float)sv[0];  x[1] = mi[1] ? -1e9f : (float)sv[1];
    x[2] = mi[2] ? -1e9f : (float)sv[2];  x[3] = mi[3] ? -1e9f : (float)sv[3];
  }
  float mx = fmaxf(fmaxf(x[0], x[1]), fmaxf(x[2], x[3]));
#pragma unroll
  for (int off = 32; off >= 1; off >>= 1) mx = fmaxf(mx, __shfl_xor(mx, off));
  if (lane == 0) red[w] = mx;
  __syncthreads();
  mx = fmaxf(fmaxf(fmaxf(red[0], red[1]), fmaxf(red[2], red[3])), fb);
  float e0 = expf(x[0] - mx), e1 = expf(x[1] - mx), e2 = expf(x[2] - mx), e3 = expf(x[3] - mx);
  float sum = (e0 + e1) + (e2 + e3);
#pragma unroll
  for (int off = 32; off >= 1; off >>= 1) sum += __shfl_xor(sum, off);
  if (lane == 0) red[4 + w] = sum;
  __syncthreads();
  float efb = expf(fb - mx);
  float Z = ((red[4] + red[5]) + (red[6] + red[7])) + efb;
  float inv = 1.0f / Z;
  f16x4 o = { (f16)(e0 * inv), (f16)(e1 * inv), (f16)(e2 * inv), (f16)(e3 * inv) };
  *(f16x4*)&Wt[(size_t)row * 1024 + k0] = o;
  if (tid == 0) wfb[row] = efb * inv;
}

// wave-per-output FC: Y[b,j] = act(X[b,:] . W[j,:] + bias[j])
template<int IN, int ACT>
__global__ __launch_bounds__(256)
void fc_wave(const float* __restrict__ X, const float* __restrict__ W,
             const float* __restrict__ bias, float* __restrict__ Y, int OutN)
{
  const int gw   = (blockIdx.x * 256 + threadIdx.x) >> 6;
  const int lane = threadIdx.x & 63;
  const int b = gw / OutN, j = gw - b * OutN;
  const float* x  = X + (size_t)b * IN;
  const float* wr = W + (size_t)j * IN;
  float s = 0.f;
  if constexpr (IN == 512) {
    const int o = lane * 8;
    float4 x0 = *(const float4*)(x + o),  x1 = *(const float4*)(x + o + 4);
    float4 w0 = *(const float4*)(wr + o), w1 = *(const float4*)(wr + o + 4);
    s = x0.x*w0.x + x0.y*w0.y + x0.z*w0.z + x0.w*w0.w
      + x1.x*w1.x + x1.y*w1.y + x1.z*w1.z + x1.w*w1.w;
  } else {
    const int o = lane * 4;
    float4 x0 = *(const float4*)(x + o);
    float4 w0 = *(const float4*)(wr + o);
    s = x0.x*w0.x + x0.y*w0.y + x0.z*w0.z + x0.w*w0.w;
  }
#pragma unroll
  for (int off = 32; off >= 1; off >>= 1) s += __shfl_xor(s, off);
  if (lane == 0) {
    float val = s + bias[ACT == 2 ? 0 : j];
    if constexpr (ACT == 1) val = fmaxf(val, 0.f);
    if constexpr (ACT == 2) val = tanhf(val);
    Y[gw] = val;
  }
}

__global__ __launch_bounds__(256)
void y_kernel(const f16* __restrict__ h2, const float* __restrict__ W3,
              const float* __restrict__ b3, float* __restrict__ outp)
{
  int row = blockIdx.x * 16 + (threadIdx.x >> 4);
  int l   = threadIdx.x & 15;
  const f16* h = h2 + (size_t)row * 256 + l * 16;
  float s = 0.f;
#pragma unroll
  for (int j = 0; j < 16; ++j) s += (float)h[j] * W3[l * 16 + j];
#pragma unroll
  for (int off = 1; off < 16; off <<= 1) s += __shfl_xor(s, off);
  if (l == 0) outp[row] = tanhf(s + b3[0]);
}

extern "C" void kernel_launch(void* const* d_in, const int* in_sizes, int n_in,
                              void* d_out, int out_size, void* d_ws, size_t ws_size,
                              hipStream_t stream) {
  const float* uq       = (const float*)d_in[0];
  const float* q        = (const float*)d_in[1];
  const float* kk       = (const float*)d_in[2];
  const float* v        = (const float*)d_in[3];
  const void*  mask     = d_in[4];
  const float* fallback = (const float*)d_in[5];
  const float* Wv = (const float*)d_in[6];
  const float* bv = (const float*)d_in[7];
  const float* Wf = (const float*)d_in[8];
  const float* bf = (const float*)d_in[9];
  const float* W1 = (const float*)d_in[10];
  const float* b1 = (const float*)d_in[11];
  const float* W2 = (const float*)d_in[12];
  const float* b2 = (const float*)d_in[13];
  const float* W3 = (const float*)d_in[14];
  const float* b3 = (const float*)d_in[15];
  float* outp = (float*)d_out;

  char* ws = (char*)d_ws;
  const size_t MB = 1ull << 20;
  f16*  scores = (f16*)ws;
  f16*  h1b  = (f16*)ws;
  f16*  h2b  = (f16*)(ws + 16 * MB);
  f16*  vpt  = (f16*)(ws + 32 * MB);
  f16*  outb = (f16*)(ws + 48 * MB);
  f16*  wts  = (f16*)(ws + 64 * MB);
  char* cst  = ws + 112 * MB;
  f16*  Wv16 = (f16*)(cst);
  f16*  W116 = (f16*)(cst + 512 * 1024);
  f16*  W216 = (f16*)(cst + 1024 * 1024);
  float* dv   = (float*)(cst + 1280 * 1024);
  float* wfb  = (float*)(cst + 1312 * 1024);
  float* h1d  = (float*)(cst + 1376 * 1024);
  float* h2d  = (float*)(cst + 1408 * 1024);
  unsigned* mm = (unsigned*)(cst + 1424 * 1024);
  float* mmarr = (float*)(cst + 1432 * 1024);   // 2 * 256 floats

  // weight converts + dv FC + mask sniff
  front_k<<<2689, 256, 0, stream>>>(Wv, W1, W2, Wv16, W116, W216,
                                    uq, Wf, bf, dv,
                                    (const unsigned char*)mask, mm);

  // scores = q @ k^T / sqrt(512) -> f16, q/k read as f32, reg-staged to f16 LDS
  gemm256_scores<<<256, 512, 0, stream>>>(q, kk, scores, 0.04419417382415922f, mmarr);

  // row softmax (fb reduced per block)
  softmax_rows<<<16384, 256, 0, stream>>>(scores, mask, fallback, mmarr, mm, wts, wfb);

  // vpt[d][k] = sum_e Wv[d][e] v[k][e] + bv[d]  (v read f32 directly)
  gemm_vpt<<<512, 256, 0, stream>>>(Wv16, v, vpt, bv);

  // out = weights @ vp + wfb*dv
  gemm_bt<EPI_OUT, true><<<512, 256, 0, stream>>>(
      wts, vpt, outb, 1024, 1024, 512, 1024,
      1048576LL, 524288LL, 524288LL,
      nullptr, 1.f, wfb, dv, 4, 32);

  // h1 = relu(out @ W1^T + b1)
  gemm_bt<EPI_RELU, false><<<512, 256, 0, stream>>>(
      outb, W116, h1b, 512, 512, 512, 512, 0LL, 0LL, 0LL,
      b1, 1.f, nullptr, nullptr, 4, 512);

  // h2 = relu(h1 @ W2^T + b2)
  gemm_bt<EPI_RELU, false><<<256, 256, 0, stream>>>(
      h1b, W216, h2b, 512, 512, 256, 512, 0LL, 0LL, 0LL,
      b2, 1.f, nullptr, nullptr, 2, 256);

  y_kernel<<<1024, 256, 0, stream>>>(h2b, W3, b3, outp);

  // default-values scorer branch (f32, wave-per-output)
  fc_wave<512, 1><<<2048, 256, 0, stream>>>(dv, W1, b1, h1d, 512);
  fc_wave<512, 1><<<1024, 256, 0, stream>>>(h1d, W2, b2, h2d, 256);
  fc_wave<256, 2><<<4, 256, 0, stream>>>(h2d, W3, b3, outp + 16384, 1);

  (void)in_sizes; (void)n_in; (void)out_size; (void)ws_size;
}